// Round 3
// baseline (20185.283 us; speedup 1.0000x reference)
//
#include <hip/hip_runtime.h>
#include <stdint.h>

// Fixed problem geometry (setup_inputs)
static constexpr int P = 8192;   // positives
static constexpr int C = 16384;  // cached
static constexpr int D = 256;    // embedding dim
static constexpr int S = 64;     // num_to_sample

__device__ __forceinline__ uint32_t rotl32(uint32_t x, uint32_t r) {
  return __builtin_amdgcn_alignbit(x, x, 32u - r);  // rotl(x,r)
}

#define TF_RND(r) { x0 += x1; x1 = rotl32(x1, r); x1 ^= x0; }

// threefry2x32 rounds AFTER the round-0 key injection. Injection words are
// wave-uniform (SALU): kA=(K1,K2+1) kB=(K2,K0+2) kC=(K0,K1+3) kD=(K1,K2+4)
// kE=(K2,K0+5). Returns x0 ^ x1 (JAX partitionable 32-bit combine).
__device__ __forceinline__ uint32_t tf_body_xor(
    uint32_t x0, uint32_t x1,
    uint32_t kA0, uint32_t kA1, uint32_t kB0, uint32_t kB1,
    uint32_t kC0, uint32_t kC1, uint32_t kD0, uint32_t kD1,
    uint32_t kE0, uint32_t kE1) {
  TF_RND(13u) TF_RND(15u) TF_RND(26u) TF_RND(6u)
  x0 += kA0; x1 += kA1;
  TF_RND(17u) TF_RND(29u) TF_RND(16u) TF_RND(24u)
  x0 += kB0; x1 += kB1;
  TF_RND(13u) TF_RND(15u) TF_RND(26u) TF_RND(6u)
  x0 += kC0; x1 += kC1;
  TF_RND(17u) TF_RND(29u) TF_RND(16u) TF_RND(24u)
  x0 += kD0; x1 += kD1;
  TF_RND(13u) TF_RND(15u) TF_RND(26u) TF_RND(6u)
  x0 += kE0; x1 += kE1;
  return x0 ^ x1;
}

// Full threefry2x32 (with round-0 injection), both output words kept.
__device__ __forceinline__ void tf_full(uint32_t k0, uint32_t k1,
                                        uint32_t &x0, uint32_t &x1) {
  const uint32_t k2 = k0 ^ k1 ^ 0x1BD11BDAu;
  x0 += k0; x1 += k1;
  TF_RND(13u) TF_RND(15u) TF_RND(26u) TF_RND(6u)
  x0 += k1; x1 += k2 + 1u;
  TF_RND(17u) TF_RND(29u) TF_RND(16u) TF_RND(24u)
  x0 += k2; x1 += k0 + 2u;
  TF_RND(13u) TF_RND(15u) TF_RND(26u) TF_RND(6u)
  x0 += k0; x1 += k1 + 3u;
  TF_RND(17u) TF_RND(29u) TF_RND(16u) TF_RND(24u)
  x0 += k1; x1 += k2 + 4u;
  TF_RND(13u) TF_RND(15u) TF_RND(26u) TF_RND(6u)
  x0 += k2; x1 += k0 + 5u;
}

// K1: inv_norm[c] = 1 / max(||emb[c]||_2, 1e-6)
__global__ __launch_bounds__(256) void norm_kernel(const float* __restrict__ emb,
                                                   float* __restrict__ inv_norm) {
  const int c = blockIdx.x;
  const int t = threadIdx.x;
  float v = emb[(size_t)c * D + t];
  float ss = v * v;
  for (int off = 32; off > 0; off >>= 1) ss += __shfl_down(ss, off, 64);
  __shared__ float part[4];
  if ((t & 63) == 0) part[t >> 6] = ss;
  __syncthreads();
  if (t == 0) {
    float tot = part[0] + part[1] + part[2] + part[3];
    inv_norm[c] = 1.0f / fmaxf(sqrtf(tot), 1e-6f);
  }
}

// K2: bm[p][w] = 64 validity bits (bit k <-> column w*64+k)
__global__ __launch_bounds__(256) void mask_kernel(const int* __restrict__ pos_ids,
                                                   const int* __restrict__ jseq,
                                                   const int* __restrict__ cids,
                                                   const int* __restrict__ cseq,
                                                   uint64_t* __restrict__ bm) {
  const int p = blockIdx.x;
  const int t = threadIdx.x;
  const int pid = pos_ids[p];
  const int js = jseq[p];
  for (int it = 0; it < C / 256; ++it) {
    const int c = it * 256 + t;
    const bool valid = (js != cseq[c]) && (pid != cids[c]);
    const uint64_t bal = __ballot(valid);
    if ((t & 63) == 0) bm[p * (C / 64) + (c >> 6)] = bal;
  }
}

// Process one 32-column mask word, columns descending (bit31 first).
// W's bit k corresponds to the column with in-thread index (vj at that step).
__device__ __forceinline__ void half_word(
    uint32_t W, uint32_t &vj, uint32_t &x1c, uint32_t &best,
    uint32_t K0, uint32_t K1, uint32_t K2,
    uint32_t kA1, uint32_t kB1, uint32_t kC1, uint32_t kD1, uint32_t kE1) {
  #pragma unroll 4
  for (int k = 0; k < 32; ++k) {
    const uint32_t bits = tf_body_xor(K0, x1c,
                                      K1, kA1, K2, kB1, K0, kC1, K1, kD1, K2, kE1);
    // top-23 = mantissa, low-9 = 511-vj: u32 max == (max mantissa, min column)
    uint32_t val = (bits | 0x1FFu) ^ vj;
    const uint32_t sm = (uint32_t)((int32_t)W >> 31);  // valid(bit31) ? ~0 : 0
    val &= sm;
    best = (best >= val) ? best : val;  // strict: keeps first on equal
    W <<= 1; --vj; --x1c;
  }
}

// K3: one WAVE per (s,p). Each lane owns 256 contiguous columns; argmax over
// valid c of (threefry_bits(s, p*C+c) >> 9) with first-index tie-break, then
// fused normalized-embedding gather (float4 coalesced row store).
__global__ __launch_bounds__(256) void sample_kernel(
    const int* __restrict__ cids, const float* __restrict__ emb,
    const float* __restrict__ inv_norm, const uint32_t* __restrict__ bm32,
    float* __restrict__ out_ids, float* __restrict__ out_emb) {
  const int bid = blockIdx.x;            // grid = (S/4) * P
  const int p = bid & (P - 1);
  const int t = threadIdx.x;
  const int wave = t >> 6;
  const int lane = t & 63;
  const int s = (bid >> 13) * 4 + wave;  // this wave's sample index

  // subkey[s] = threefry((0,42), (0,s))  [partitionable fold-like split]
  uint32_t a0 = 0u, a1 = (uint32_t)s;
  tf_full(0u, 42u, a0, a1);
  const uint32_t K0 = (uint32_t)__builtin_amdgcn_readfirstlane((int)a0);
  const uint32_t K1 = (uint32_t)__builtin_amdgcn_readfirstlane((int)a1);
  const uint32_t K2 = K0 ^ K1 ^ 0x1BD11BDAu;
  const uint32_t kA1 = K2 + 1u, kB1 = K0 + 2u, kC1 = K1 + 3u,
                 kD1 = K2 + 4u, kE1 = K0 + 5u;

  // Lane's validity mask: 8 x uint32 words (columns [lane*256, lane*256+256))
  const uint32_t* mrow = bm32 + (size_t)p * (C / 32) + lane * 8;
  const uint4 ma = *(const uint4*)(mrow);      // words 0..3  (cols 0..127)
  const uint4 mb = *(const uint4*)(mrow + 4);  // words 4..7  (cols 128..255)

  const uint32_t fbase = ((uint32_t)p << 14) | ((uint32_t)lane << 8);  // p*C + lane*256
  uint32_t vj = 255u;                 // in-thread column index, descending
  uint32_t x1c = fbase + K1 + 255u;   // counter + round-0 injection, descending
  uint32_t best = 0u;

  half_word(mb.w, vj, x1c, best, K0, K1, K2, kA1, kB1, kC1, kD1, kE1);
  half_word(mb.z, vj, x1c, best, K0, K1, K2, kA1, kB1, kC1, kD1, kE1);
  half_word(mb.y, vj, x1c, best, K0, K1, K2, kA1, kB1, kC1, kD1, kE1);
  half_word(mb.x, vj, x1c, best, K0, K1, K2, kA1, kB1, kC1, kD1, kE1);
  half_word(ma.w, vj, x1c, best, K0, K1, K2, kA1, kB1, kC1, kD1, kE1);
  half_word(ma.z, vj, x1c, best, K0, K1, K2, kA1, kB1, kC1, kD1, kE1);
  half_word(ma.y, vj, x1c, best, K0, K1, K2, kA1, kB1, kC1, kD1, kE1);
  half_word(ma.x, vj, x1c, best, K0, K1, K2, kA1, kB1, kC1, kD1, kE1);

  // Global comparable key: (mantissa << 14) | (16383 - c) -> max m, then min c.
  // (If a row were fully masked best==0 for all lanes; cannot occur with this
  //  data distribution: P(all 16384 cols invalid) ~ 0.008^16384.)
  unsigned long long g = 0ull;
  if (best) {
    const uint32_t jj = 511u - (best & 511u);          // == winning vj (0..255)
    const uint32_t c = ((uint32_t)lane << 8) + jj;
    g = ((unsigned long long)(best >> 9) << 14) | (unsigned long long)(16383u - c);
  }
  #pragma unroll
  for (int off = 32; off > 0; off >>= 1) {
    unsigned long long o = __shfl_down(g, off, 64);
    g = (o > g) ? o : g;
  }
  const uint32_t glo = (uint32_t)__builtin_amdgcn_readfirstlane((int)(uint32_t)g);
  const uint32_t ghi = (uint32_t)__builtin_amdgcn_readfirstlane((int)(uint32_t)(g >> 32));
  const uint32_t cwin = 16383u - (((ghi << 18) | (glo)) & 16383u);  // low 14 bits

  // Fused gather: normalized embedding row (float4, coalesced) + sampled id
  const float scale = inv_norm[cwin];
  const float4 e = *(const float4*)(emb + (size_t)cwin * D + lane * 4);
  float4 r;
  r.x = e.x * scale; r.y = e.y * scale; r.z = e.z * scale; r.w = e.w * scale;
  const size_t orow = (size_t)p * S + s;
  *(float4*)(out_emb + orow * D + lane * 4) = r;
  if (lane == 0) out_ids[orow] = (float)cids[cwin];
}

extern "C" void kernel_launch(void* const* d_in, const int* in_sizes, int n_in,
                              void* d_out, int out_size, void* d_ws, size_t ws_size,
                              hipStream_t stream) {
  const int*   pos_ids = (const int*)d_in[0];
  const int*   jseq    = (const int*)d_in[1];
  const int*   cids    = (const int*)d_in[2];
  const int*   cseq    = (const int*)d_in[3];
  const float* emb     = (const float*)d_in[4];
  // d_in[5] = num_to_sample (==64, fixed)

  float* out_ids = (float*)d_out;              // P*S floats
  float* out_emb = out_ids + (size_t)P * S;    // P*S*D floats

  float*    inv_norm = (float*)d_ws;                 // C floats (64 KiB)
  uint64_t* bm = (uint64_t*)((char*)d_ws + 65536);   // P * C/64 u64 (16 MiB)

  norm_kernel<<<C, 256, 0, stream>>>(emb, inv_norm);
  mask_kernel<<<P, 256, 0, stream>>>(pos_ids, jseq, cids, cseq, bm);
  sample_kernel<<<(S / 4) * P, 256, 0, stream>>>(cids, emb, inv_norm,
                                                 (const uint32_t*)bm,
                                                 out_ids, out_emb);
}